// Round 7
// baseline (258.436 us; speedup 1.0000x reference)
//
#include <hip/hip_runtime.h>
#include <hip/hip_bf16.h>

typedef __bf16 bf16_t;
typedef __bf16 bf16x4 __attribute__((ext_vector_type(4)));
typedef __bf16 bf16x8 __attribute__((ext_vector_type(8)));
typedef float f32x16 __attribute__((ext_vector_type(16)));

#define E_DIM 1024
#define SEQ   2048
#define NBATCH 4

// ---------------- weight casts (4 x 1024x1024 f32 -> bf16) ----------------
__global__ __launch_bounds__(256) void k_castw(
    const float* __restrict__ wq, const float* __restrict__ wk,
    const float* __restrict__ wv, const float* __restrict__ wo,
    bf16_t* __restrict__ wqb, bf16_t* __restrict__ wkb,
    bf16_t* __restrict__ wvb, bf16_t* __restrict__ wob) {
  const int b = blockIdx.x;
  const int w = b >> 9, r = b & 511;
  const float* s = (w == 0) ? wq : (w == 1) ? wk : (w == 2) ? wv : wo;
  bf16_t* d = (w == 0) ? wqb : (w == 1) ? wkb : (w == 2) ? wvb : wob;
  const long i = (long)r * 2048 + threadIdx.x * 8;
  const float4 a = *(const float4*)(s + i);
  const float4 c = *(const float4*)(s + i + 4);
  bf16x8 o;
  o[0] = (bf16_t)a.x; o[1] = (bf16_t)a.y; o[2] = (bf16_t)a.z; o[3] = (bf16_t)a.w;
  o[4] = (bf16_t)c.x; o[5] = (bf16_t)c.y; o[6] = (bf16_t)c.z; o[7] = (bf16_t)c.w;
  *(bf16x8*)(d + i) = o;
}

// =================================================================================
// m97-structure GEMM: 128x128 tile, 4 waves (2x2), per-wave 64x64 via
// mfma_f32_32x32x16_bf16 (2x2 frags), BK=64, SINGLE LDS buffer,
// { stage(t); __syncthreads(); compute(t); __syncthreads(); }  -- NO manual
// waitcnts/barriers: the compiler emits fine-grained lgkmcnt interleave, and
// cross-block overlap (3 blocks/CU) hides the vmcnt drain at the barrier.
// A: AF32 ? f32 [M][K] staged as f32 (32KB, 16-slot XOR swizzle, cvt at read)
//          : bf16 [M][K] staged (16KB, 8-slot XOR swizzle).
// B: bf16 [N][K] staged (16KB). T2: linear GLL dest + inverse-swizzled source.
// OUTMODE 0: f32 + bias + residual, 1: bf16 + bias, 2: bf16 transposed
// (Vt[b][col][s]) + bias, 3: bf16 exp(v*scale).
// RS: ones-MFMA row sums of A (PV normalize), scale rows by 1/rs.
// =================================================================================
template <int OUTMODE, bool RS, bool AF32>
__global__ __launch_bounds__(256, RS ? 2 : 3) void k_g7(
    const void* __restrict__ Av, int lda, long sA,
    const bf16_t* __restrict__ B, int ldb, long sB,
    void* __restrict__ Cv, int ldc, long sC,
    int K, float scale, const float* __restrict__ bias,
    const float* __restrict__ residual, int GM, int GN) {
  constexpr int ABYTES = AF32 ? 32768 : 16384;
  __shared__ __align__(16) char smem[ABYTES + 16384];

  const int tid  = threadIdx.x;
  const int lane = tid & 63;
  const int wid  = tid >> 6;
  const int wm   = wid >> 1, wn = wid & 1;
  const int hi   = lane >> 5;
  const int l31  = lane & 31;

  // T1: XCD swizzle (grid always a multiple of 8)
  const int nwg  = gridDim.x;
  const int orig = blockIdx.x;
  const int wg   = (orig & 7) * (nwg >> 3) + (orig >> 3);
  const int zz   = wg / (GM * GN);
  const int rm   = wg - zz * (GM * GN);
  const int bm   = rm / GN;
  const int bn   = rm - bm * GN;
  const int brow = bm * 128;
  const int bcol = bn * 128;

#define GLL(gaddr, ldsoff)                                                       \
  __builtin_amdgcn_global_load_lds(                                             \
      (const __attribute__((address_space(1))) void*)(gaddr),                   \
      (__attribute__((address_space(3))) void*)(smem + (ldsoff)), 16, 0, 0)

  // staging sources (inverse-XOR-swizzled cols; LDS dest linear per rule 21)
  const float*  A32s = AF32 ? (const float*)Av + zz * sA +
                              (long)(brow + (tid >> 4)) * lda +
                              (((tid & 15) ^ ((tid >> 4) & 15)) << 2)
                            : nullptr;
  const bf16_t* A16s = AF32 ? nullptr
                            : (const bf16_t*)Av + zz * sA +
                              (long)(brow + (tid >> 3)) * lda +
                              (((tid & 7) ^ ((tid >> 3) & 7)) << 3);
  const bf16_t* Bs   = B + zz * sB + (long)(bcol + (tid >> 3)) * ldb +
                       (((tid & 7) ^ ((tid >> 3) & 7)) << 3);
  const int ldsw = wid << 10;

  auto stage = [&](int t) {
    const long koff = (long)t * 64;
    if constexpr (AF32) {
#pragma unroll
      for (int s = 0; s < 8; ++s)
        GLL(A32s + (long)(s * 16) * lda + koff, s * 4096 + ldsw);
    } else {
#pragma unroll
      for (int s = 0; s < 4; ++s)
        GLL(A16s + (long)(s * 32) * lda + koff, s * 4096 + ldsw);
    }
#pragma unroll
    for (int s = 0; s < 4; ++s)
      GLL(Bs + (long)(s * 32) * ldb + koff, ABYTES + s * 4096 + ldsw);
  };

  // fragment reads (swizzled)
  auto ldA = [&](int kk, int ra) -> bf16x8 {
    if constexpr (AF32) {
      const int b = kk * 64 + (hi << 5);
      const int sw = (ra & 15) << 4;
      const float4 f0 = *(const float4*)(smem + ra * 256 + (b ^ sw));
      const float4 f1 = *(const float4*)(smem + ra * 256 + ((b + 16) ^ sw));
      bf16x8 r;
      r[0] = (bf16_t)f0.x; r[1] = (bf16_t)f0.y; r[2] = (bf16_t)f0.z; r[3] = (bf16_t)f0.w;
      r[4] = (bf16_t)f1.x; r[5] = (bf16_t)f1.y; r[6] = (bf16_t)f1.z; r[7] = (bf16_t)f1.w;
      return r;
    } else {
      const int b = kk * 32 + (hi << 4);
      return *(const bf16x8*)(smem + ra * 128 + (b ^ ((ra & 7) << 4)));
    }
  };
  auto ldB = [&](int kk, int rb) -> bf16x8 {
    const int b = kk * 32 + (hi << 4);
    return *(const bf16x8*)(smem + ABYTES + rb * 128 + (b ^ ((rb & 7) << 4)));
  };

  f32x16 acc00 = {}, acc01 = {}, acc10 = {}, acc11 = {};
  f32x16 rs0 = {}, rs1 = {};
  bf16x8 vones;
#pragma unroll
  for (int i = 0; i < 8; ++i) vones[i] = (bf16_t)1.0f;

  const int ra = wm * 64 + l31;
  const int rb = wn * 64 + l31;
  const int NT = K >> 6;

  for (int t = 0; t < NT; ++t) {
    stage(t);
    __syncthreads();
#pragma unroll
    for (int k = 0; k < 4; ++k) {
      bf16x8 a0 = ldA(k, ra), a1 = ldA(k, ra + 32);
      bf16x8 b0 = ldB(k, rb), b1 = ldB(k, rb + 32);
      acc00 = __builtin_amdgcn_mfma_f32_32x32x16_bf16(a0, b0, acc00, 0, 0, 0);
      acc01 = __builtin_amdgcn_mfma_f32_32x32x16_bf16(a0, b1, acc01, 0, 0, 0);
      acc10 = __builtin_amdgcn_mfma_f32_32x32x16_bf16(a1, b0, acc10, 0, 0, 0);
      acc11 = __builtin_amdgcn_mfma_f32_32x32x16_bf16(a1, b1, acc11, 0, 0, 0);
      if constexpr (RS) {
        rs0 = __builtin_amdgcn_mfma_f32_32x32x16_bf16(a0, vones, rs0, 0, 0, 0);
        rs1 = __builtin_amdgcn_mfma_f32_32x32x16_bf16(a1, vones, rs1, 0, 0, 0);
      }
    }
    __syncthreads();
  }

  // Epilogue. 32x32 C/D layout (m74/m101): col = lane&31, row = (reg&3)+8*(reg>>2)+4*hi
  float inv0[16], inv1[16];
  if constexpr (RS) {
#pragma unroll
    for (int i = 0; i < 16; ++i) { inv0[i] = 1.0f / rs0[i]; inv1[i] = 1.0f / rs1[i]; }
  }
  const int colb = bcol + wn * 64 + l31;
  const int rowb = brow + wm * 64 + (hi << 2);
#pragma unroll
  for (int mf = 0; mf < 2; ++mf) {
#pragma unroll
    for (int nf = 0; nf < 2; ++nf) {
      const f32x16 av = (mf == 0) ? (nf == 0 ? acc00 : acc01) : (nf == 0 ? acc10 : acc11);
      const int colg = colb + nf * 32;
      float bval = 0.0f;
      if constexpr (OUTMODE != 3) bval = bias ? bias[colg] : 0.0f;
#pragma unroll
      for (int g = 0; g < 4; ++g) {
        const int r0 = rowb + mf * 32 + g * 8;
        if constexpr (OUTMODE == 2) {
          bf16x4 pk;
#pragma unroll
          for (int j = 0; j < 4; ++j) pk[j] = (bf16_t)(av[g * 4 + j] * scale + bval);
          const long bb = (long)(r0 >> 11);
          const int ss = r0 & (SEQ - 1);
          *(bf16x4*)((bf16_t*)Cv + bb * ((long)E_DIM * SEQ) + (long)colg * SEQ + ss) = pk;
        } else {
#pragma unroll
          for (int j = 0; j < 4; ++j) {
            const int r = r0 + j;
            float v;
            if constexpr (OUTMODE == 3) v = __expf(av[g * 4 + j] * scale);
            else v = av[g * 4 + j] * scale + bval;
            if constexpr (RS) v *= (mf == 0 ? inv0[g * 4 + j] : inv1[g * 4 + j]);
            if (OUTMODE == 0 && residual) v += residual[(long)r * ldc + colg];
            const long idx = (long)zz * sC + (long)r * ldc + colg;
            if constexpr (OUTMODE == 0) ((float*)Cv)[idx] = v;
            else ((bf16_t*)Cv)[idx] = (bf16_t)v;
          }
        }
      }
    }
  }
#undef GLL
}

// ---------------- layernorm in-place on rows of 1024 f32 ----------------
__global__ __launch_bounds__(256) void k_layernorm(float* __restrict__ out,
                                                   const float* __restrict__ gamma,
                                                   const float* __restrict__ beta) {
  const long row = blockIdx.x;
  float* rp = out + row * 1024;
  const int t = threadIdx.x;
  const float4 v = *(const float4*)(rp + t * 4);
  float s = v.x + v.y + v.z + v.w;
#pragma unroll
  for (int o = 32; o; o >>= 1) s += __shfl_xor(s, o);
  __shared__ float red1[4], red2[4];
  const int lane = t & 63, w = t >> 6;
  if (lane == 0) red1[w] = s;
  __syncthreads();
  const float mu = (red1[0] + red1[1] + red1[2] + red1[3]) * (1.0f / 1024.0f);
  const float d0 = v.x - mu, d1 = v.y - mu, d2 = v.z - mu, d3 = v.w - mu;
  float ss = d0 * d0 + d1 * d1 + d2 * d2 + d3 * d3;
#pragma unroll
  for (int o = 32; o; o >>= 1) ss += __shfl_xor(ss, o);
  if (lane == 0) red2[w] = ss;
  __syncthreads();
  const float var = (red2[0] + red2[1] + red2[2] + red2[3]) * (1.0f / 1024.0f);
  const float rsq = rsqrtf(var + 1e-6f);
  const float4 g = *(const float4*)(gamma + t * 4);
  const float4 b = *(const float4*)(beta + t * 4);
  float4 o;
  o.x = d0 * rsq * g.x + b.x;
  o.y = d1 * rsq * g.y + b.y;
  o.z = d2 * rsq * g.z + b.z;
  o.w = d3 * rsq * g.w + b.w;
  *(float4*)(rp + t * 4) = o;
}

extern "C" void kernel_launch(void* const* d_in, const int* in_sizes, int n_in,
                              void* d_out, int out_size, void* d_ws, size_t ws_size,
                              hipStream_t stream) {
  const float* query = (const float*)d_in[0];
  const float* key   = (const float*)d_in[1];
  const float* value = (const float*)d_in[2];
  const float* Wq = (const float*)d_in[3];
  const float* bq = (const float*)d_in[4];
  const float* Wk = (const float*)d_in[5];
  const float* bk = (const float*)d_in[6];
  const float* Wv = (const float*)d_in[7];
  const float* bv = (const float*)d_in[8];
  const float* Wo = (const float*)d_in[9];
  const float* bo = (const float*)d_in[10];
  const float* gamma = (const float*)d_in[11];
  const float* beta  = (const float*)d_in[12];
  float* out = (float*)d_out;

  char* ws = (char*)d_ws;
  const size_t XSZ = (size_t)NBATCH * SEQ * E_DIM * 2;  // 16 MiB
  const size_t WSZ = (size_t)E_DIM * E_DIM * 2;         // 2 MiB
  const size_t B2  = 3 * XSZ;                           // 48 MiB boundary

  bf16_t* SC  = (bf16_t*)(ws + 0);            // exp-scores, 33.5 MB
  bf16_t* Wqb = (bf16_t*)(ws + B2);
  bf16_t* Wkb = (bf16_t*)(ws + B2 + WSZ);
  bf16_t* Wvb = (bf16_t*)(ws + B2 + 2 * WSZ);
  bf16_t* Wob = (bf16_t*)(ws + B2 + 3 * WSZ);
  bf16_t* Qb  = (bf16_t*)(ws + B2 + 4 * WSZ);
  bf16_t* Kb  = (bf16_t*)(ws + B2 + 4 * WSZ + XSZ);
  bf16_t* Vt  = (bf16_t*)(ws + B2 + 4 * WSZ + 2 * XSZ);
  bf16_t* Ctx = (bf16_t*)(ws + B2 + 4 * WSZ + 3 * XSZ);

  const int NTOK = NBATCH * SEQ;  // 8192

  // 1) weight casts only (X is consumed f32 directly by the projections)
  k_castw<<<dim3(2048), 256, 0, stream>>>(Wq, Wk, Wv, Wo, Wqb, Wkb, Wvb, Wob);

  // 2) projections, f32-A staging (grid 64x8 = 512, 3 blocks/CU capacity)
  k_g7<1, false, true><<<512, 256, 0, stream>>>(
      query, E_DIM, 0, Wqb, E_DIM, 0, Qb, E_DIM, 0, E_DIM, 1.0f, bq, nullptr, 64, 8);
  k_g7<1, false, true><<<512, 256, 0, stream>>>(
      key, E_DIM, 0, Wkb, E_DIM, 0, Kb, E_DIM, 0, E_DIM, 1.0f, bk, nullptr, 64, 8);
  k_g7<2, false, true><<<512, 256, 0, stream>>>(
      value, E_DIM, 0, Wvb, E_DIM, 0, Vt, 0, 0, E_DIM, 1.0f, bv, nullptr, 64, 8);

  // 3) P = exp(Q K^T / 32) -> bf16 (grid 16x16x4 = 1024)
  k_g7<3, false, false><<<1024, 256, 0, stream>>>(
      Qb, E_DIM, (long)SEQ * E_DIM, Kb, E_DIM, (long)SEQ * E_DIM,
      SC, SEQ, (long)SEQ * SEQ, E_DIM, 0.03125f, nullptr, nullptr, 16, 16);

  // 4) ctx = (P @ V) / rowsum — rowsum via ones-MFMA, lane-local normalize
  //    (grid 16x8x4 = 512)
  k_g7<1, true, false><<<512, 256, 0, stream>>>(
      SC, SEQ, (long)SEQ * SEQ, Vt, SEQ, (long)E_DIM * SEQ,
      Ctx, E_DIM, (long)SEQ * E_DIM, SEQ, 1.0f, nullptr, nullptr, 16, 8);

  // 5) out = ctx Wo^T + bo + residual(query), f32 into d_out (grid 512)
  k_g7<0, false, false><<<512, 256, 0, stream>>>(
      Ctx, E_DIM, 0, Wob, E_DIM, 0, out, E_DIM, 0, E_DIM, 1.0f, bo, query, 64, 8);

  // 6) layernorm in-place
  k_layernorm<<<dim3(NTOK), 256, 0, stream>>>(out, gamma, beta);
}